// Round 8
// baseline (32079.163 us; speedup 1.0000x reference)
//
#include <hip/hip_runtime.h>

// CGIterator: N=50000 nodes, K=128, I=4 chained CG iterations, fp32.
// Round-8: r7 skeleton (128 thr, NB=2, TN=2-consecutive, float2 weight loads)
// + K-step-4 DOUBLE-BUFFERED weight prefetch in both linear layers.
// LDS (30 KB -> 5 blocks/CU) is the binding occupancy limit, so VGPR up to
// 170 is free: __launch_bounds__(128,3) gives the allocator room for the
// second buffer (wa+wb = 48 regs) without spilling or losing waves.

#define NNODES 50000
#define KCH 128          // K
#define PCH 256          // 2K
#define NITER 4
#define NB 2             // nodes per block
#define NTHR 128

// ---- linear_in: weights buf = float2[3][4] at column pair (2t,2t+1) ----
#define LOADWIN(buf, kb) do { \
    _Pragma("unroll") \
    for (int r = 0; r < 4; ++r) { \
        buf[0][r] = *(const float2*)&W0[((kb) + r) * PCH]; \
        buf[1][r] = *(const float2*)&W1[((kb) + r) * PCH]; \
        buf[2][r] = *(const float2*)&W2[((kb) + r) * PCH]; \
    } \
} while (0)

#define INSTEP(buf, kb) do { \
    _Pragma("unroll") \
    for (int n = 0; n < NB; ++n) { \
        _Pragma("unroll") \
        for (int m = 0; m < 9; ++m) { \
            const int lm = (m == 0) ? 0 : ((m < 4) ? 1 : 2); \
            const float4 h4 = *(const float4*)&s_h[n][m][(kb)]; \
            float a = hcA[n][m], b = hcB[n][m]; \
            a = fmaf(h4.x, buf[lm][0].x, a); \
            a = fmaf(h4.y, buf[lm][1].x, a); \
            a = fmaf(h4.z, buf[lm][2].x, a); \
            a = fmaf(h4.w, buf[lm][3].x, a); \
            b = fmaf(h4.x, buf[lm][0].y, b); \
            b = fmaf(h4.y, buf[lm][1].y, b); \
            b = fmaf(h4.z, buf[lm][2].y, b); \
            b = fmaf(h4.w, buf[lm][3].y, b); \
            hcA[n][m] = a; hcB[n][m] = b; \
        } \
    } \
} while (0)

// ---- linear_out: weights buf = float2[3][4] at kk pair (2ln,2ln+1) ----
#define LOADWOUT(buf, pb) do { \
    _Pragma("unroll") \
    for (int r = 0; r < 4; ++r) { \
        const size_t row_ = (size_t)(pb0 + (pb) + r) * KCH; \
        buf[0][r] = *(const float2*)&V0[row_]; \
        buf[1][r] = *(const float2*)&V1[row_]; \
        buf[2][r] = *(const float2*)&V2[row_]; \
    } \
} while (0)

#define OUTSTEP(buf, pb) do { \
    _Pragma("unroll") \
    for (int n = 0; n < NB; ++n) { \
        _Pragma("unroll") \
        for (int m = 0; m < 9; ++m) { \
            const int lm = (m == 0) ? 0 : ((m < 4) ? 1 : 2); \
            const float4 t4 = *(const float4*)&s_tp[n][m][pb0 + (pb)]; \
            float a = oaA[n][m], b = oaB[n][m]; \
            a = fmaf(t4.x, buf[lm][0].x, a); \
            a = fmaf(t4.y, buf[lm][1].x, a); \
            a = fmaf(t4.z, buf[lm][2].x, a); \
            a = fmaf(t4.w, buf[lm][3].x, a); \
            b = fmaf(t4.x, buf[lm][0].y, b); \
            b = fmaf(t4.y, buf[lm][1].y, b); \
            b = fmaf(t4.z, buf[lm][2].y, b); \
            b = fmaf(t4.w, buf[lm][3].y, b); \
            oaA[n][m] = a; oaB[n][m] = b; \
        } \
    } \
} while (0)

__global__ __launch_bounds__(NTHR, 3)
void cg_fused(const float* __restrict__ f0,
              const float* __restrict__ f1,
              const float* __restrict__ f2,
              const float* __restrict__ Uin,
              const float* __restrict__ gamma,
              const float* __restrict__ W_in,
              const float* __restrict__ W_out,
              float* __restrict__ out)
{
    // symmetrized U, upper triangle a<=b packed: sUp[ab][c], c padded to 12
    __shared__ float sUp[45][12];                 // 2.1 KB
    __shared__ float s_h[NB][9][KCH];             // 9.2 KB
    __shared__ float s_tp[NB][9][PCH];            // 18.4 KB; dead after lin_out
                                                  // reads -> reused for exchange
    // exchange view over s_tp: s_part[wave][j=n*9+m][kk], 2*18*128*4B = 18.4KB
    float (*s_part)[18][KCH] = reinterpret_cast<float (*)[18][KCH]>(&s_tp[0][0][0]);

    const int tid = threadIdx.x;      // 0..127
    const int w   = tid >> 6;         // wave: 0 or 1 (uniform per wave)
    const int ln  = tid & 63;
    const int kk  = tid;              // owned channel for RMS/skip/output
    const int node0 = blockIdx.x * NB;

    // ---- build symmetrized padded U in LDS (once per block)
    for (int idx = tid; idx < 45 * 12; idx += NTHR) {
        const int ab = idx / 12;
        const int c  = idx % 12;
        int a = 0, r = ab;
        while (r >= 9 - a) { r -= 9 - a; ++a; }
        const int b = a + r;
        float v = 0.0f;
        if (c < 9) {
            v = Uin[(a * 9 + b) * 9 + c];
            if (a != b) v += Uin[(b * 9 + a) * 9 + c];
        }
        sUp[ab][c] = v;
    }

    // ---- initial feats: thread owns channel kk for BOTH nodes, all 9 m
    float f[NB][9];
    #pragma unroll
    for (int n = 0; n < NB; ++n) {
        const int ng = node0 + n;
        f[n][0] = f0[ng * KCH + kk];
        #pragma unroll
        for (int m = 0; m < 3; ++m) f[n][1 + m] = f1[(ng * 3 + m) * KCH + kk];
        #pragma unroll
        for (int m = 0; m < 5; ++m) f[n][4 + m] = f2[(ng * 5 + m) * KCH + kk];
    }

    for (int it = 0; it < NITER; ++it) {
        // ---------- step 1: equivariant RMS norm -> s_h ----------
        {
            const float g0 = gamma[(it * 3 + 0) * KCH + kk];
            const float g1 = gamma[(it * 3 + 1) * KCH + kk];
            const float g2 = gamma[(it * 3 + 2) * KCH + kk];
            #pragma unroll
            for (int n = 0; n < NB; ++n) {
                const float s0 = f[n][0] * f[n][0];
                const float s1 = f[n][1] * f[n][1] + f[n][2] * f[n][2] + f[n][3] * f[n][3];
                const float s2 = f[n][4] * f[n][4] + f[n][5] * f[n][5] + f[n][6] * f[n][6]
                               + f[n][7] * f[n][7] + f[n][8] * f[n][8];
                const float r0 = rsqrtf(s0 + 1e-6f) * g0;
                const float r1 = rsqrtf(s1 * (1.0f / 3.0f) + 1e-6f) * g1;
                const float r2 = rsqrtf(s2 * (1.0f / 5.0f) + 1e-6f) * g2;
                s_h[n][0][kk] = f[n][0] * r0;
                s_h[n][1][kk] = f[n][1] * r1;
                s_h[n][2][kk] = f[n][2] * r1;
                s_h[n][3][kk] = f[n][3] * r1;
                s_h[n][4][kk] = f[n][4] * r2;
                s_h[n][5][kk] = f[n][5] * r2;
                s_h[n][6][kk] = f[n][6] * r2;
                s_h[n][7][kk] = f[n][7] * r2;
                s_h[n][8][kk] = f[n][8] * r2;
            }
        }
        __syncthreads();   // s_h visible (also orders sUp build on it==0)

        // ---------- step 2: linear_in, TN=2 float2 weights, K4 double-buffered
        float hcA[NB][9], hcB[NB][9];   // A = col 2t, B = col 2t+1
        {
            const float* W0 = W_in + (size_t)(it * 3 + 0) * KCH * PCH + 2 * tid;
            const float* W1 = W_in + (size_t)(it * 3 + 1) * KCH * PCH + 2 * tid;
            const float* W2 = W_in + (size_t)(it * 3 + 2) * KCH * PCH + 2 * tid;
            #pragma unroll
            for (int n = 0; n < NB; ++n)
                #pragma unroll
                for (int m = 0; m < 9; ++m) { hcA[n][m] = 0.0f; hcB[n][m] = 0.0f; }

            float2 wa[3][4], wb[3][4];
            LOADWIN(wa, 0);
            #pragma unroll 1
            for (int kb = 0; kb < KCH - 8; kb += 8) {
                LOADWIN(wb, kb + 4);
                INSTEP(wa, kb);
                LOADWIN(wa, kb + 8);
                INSTEP(wb, kb + 4);
            }
            {   // tail: kb = 120, 124
                LOADWIN(wb, 124);
                INSTEP(wa, 120);
                INSTEP(wb, 124);
            }
        }

        // ---------- step 3: CG tensor product, both columns in registers ----------
        {
            float tpA[NB][9], tpB[NB][9];
            #pragma unroll
            for (int n = 0; n < NB; ++n)
                #pragma unroll
                for (int c = 0; c < 9; ++c) { tpA[n][c] = 0.0f; tpB[n][c] = 0.0f; }

            int ab = 0;
            #pragma unroll
            for (int a = 0; a < 9; ++a) {
                #pragma unroll
                for (int b = a; b < 9; ++b) {
                    const float qA0 = hcA[0][a] * hcA[0][b];
                    const float qA1 = hcA[1][a] * hcA[1][b];
                    const float qB0 = hcB[0][a] * hcB[0][b];
                    const float qB1 = hcB[1][a] * hcB[1][b];
                    const float4 u0 = *(const float4*)&sUp[ab][0];
                    const float4 u1 = *(const float4*)&sUp[ab][4];
                    const float  u8 = sUp[ab][8];
                    const float uu[9] = {u0.x, u0.y, u0.z, u0.w, u1.x, u1.y, u1.z, u1.w, u8};
                    #pragma unroll
                    for (int c = 0; c < 9; ++c) {
                        tpA[0][c] = fmaf(uu[c], qA0, tpA[0][c]);
                        tpA[1][c] = fmaf(uu[c], qA1, tpA[1][c]);
                        tpB[0][c] = fmaf(uu[c], qB0, tpB[0][c]);
                        tpB[1][c] = fmaf(uu[c], qB1, tpB[1][c]);
                    }
                    ++ab;
                }
            }
            // paired columns -> single ds_write_b64 each (2-way bank alias: free)
            #pragma unroll
            for (int n = 0; n < NB; ++n) {
                #pragma unroll
                for (int c = 0; c < 9; ++c) {
                    float2 t2; t2.x = tpA[n][c]; t2.y = tpB[n][c];
                    *(float2*)&s_tp[n][c][2 * tid] = t2;
                }
            }
        }
        __syncthreads();   // s_tp visible to all columns

        // ---------- step 4: linear_out, p-half per wave, P4 double-buffered
        float oaA[NB][9], oaB[NB][9];   // kkA = 2*ln, kkB = 2*ln+1
        {
            const float* V0 = W_out + (size_t)(it * 3 + 0) * PCH * KCH + 2 * ln;
            const float* V1 = W_out + (size_t)(it * 3 + 1) * PCH * KCH + 2 * ln;
            const float* V2 = W_out + (size_t)(it * 3 + 2) * PCH * KCH + 2 * ln;
            const int pb0 = w * 128;   // this wave's p-half (uniform)

            #pragma unroll
            for (int n = 0; n < NB; ++n)
                #pragma unroll
                for (int m = 0; m < 9; ++m) { oaA[n][m] = 0.0f; oaB[n][m] = 0.0f; }

            float2 va[3][4], vb[3][4];
            LOADWOUT(va, 0);
            #pragma unroll 1
            for (int pb = 0; pb < 128 - 8; pb += 8) {
                LOADWOUT(vb, pb + 4);
                OUTSTEP(va, pb);
                LOADWOUT(va, pb + 8);
                OUTSTEP(vb, pb + 4);
            }
            {   // tail: pb = 120, 124
                LOADWOUT(vb, 124);
                OUTSTEP(va, 120);
                OUTSTEP(vb, 124);
            }
        }
        __syncthreads();   // ALL s_tp reads done -> safe to overwrite as s_part

        // exchange: both waves write their partials for their kk-pair; each
        // thread then sums the two wave-partials at its own kk column.
        #pragma unroll
        for (int n = 0; n < NB; ++n) {
            #pragma unroll
            for (int m = 0; m < 9; ++m) {
                float2 t2; t2.x = oaA[n][m]; t2.y = oaB[n][m];
                *(float2*)&s_part[w][n * 9 + m][2 * ln] = t2;
            }
        }
        __syncthreads();

        #pragma unroll
        for (int n = 0; n < NB; ++n)
            #pragma unroll
            for (int m = 0; m < 9; ++m)
                f[n][m] += s_part[0][n * 9 + m][kk] + s_part[1][n * 9 + m][kk];
        __syncthreads();   // s_part reads done before next iter's TP rewrites s_tp
    }

    // ---------- store packed output (N, 9, K)
    #pragma unroll
    for (int n = 0; n < NB; ++n) {
        const int ng = node0 + n;
        #pragma unroll
        for (int m = 0; m < 9; ++m)
            out[(size_t)(ng * 9 + m) * KCH + kk] = f[n][m];
    }
}

extern "C" void kernel_launch(void* const* d_in, const int* in_sizes, int n_in,
                              void* d_out, int out_size, void* d_ws, size_t ws_size,
                              hipStream_t stream) {
    const float* f0    = (const float*)d_in[0];
    const float* f1    = (const float*)d_in[1];
    const float* f2    = (const float*)d_in[2];
    const float* U     = (const float*)d_in[3];
    const float* gamma = (const float*)d_in[4];
    const float* W_in  = (const float*)d_in[5];
    const float* W_out = (const float*)d_in[6];
    float* out = (float*)d_out;

    dim3 grid(NNODES / NB);   // 50000 / 2 = 25000, exact
    dim3 block(NTHR);
    hipLaunchKernelGGL(cg_fused, grid, block, 0, stream,
                       f0, f1, f2, U, gamma, W_in, W_out, out);
}

// Round 9
// 5673.524 us; speedup vs baseline: 5.6542x; 5.6542x over previous
//
#include <hip/hip_runtime.h>

// CGIterator: N=50000 nodes, K=128, I=4 chained CG iterations, fp32.
// Round-9: r7 skeleton (128 thr, NB=2, TN=2-consecutive, float2 weight loads,
// __launch_bounds__(128,4), VGPR 116, no spill) with the three hot FMA loops
// rewritten as 2-wide packed fp32 (ext_vector float2 + elementwise fma ->
// v_pk_fma_f32). Halves VALU instruction count; per-component IEEE fma is
// bit-identical to the scalar version. Everything else unchanged from r7.

#define NNODES 50000
#define KCH 128          // K
#define PCH 256          // 2K
#define NITER 4
#define NB 2             // nodes per block
#define NTHR 128

typedef float v2f __attribute__((ext_vector_type(2)));

#if __has_builtin(__builtin_elementwise_fma)
#define PKFMA(a, b, c) __builtin_elementwise_fma((a), (b), (c))
#else
static __device__ inline v2f PKFMA(v2f a, v2f b, v2f c) {
    v2f r; r.x = fmaf(a.x, b.x, c.x); r.y = fmaf(a.y, b.y, c.y); return r;
}
#endif

__global__ __launch_bounds__(NTHR, 4)
void cg_fused(const float* __restrict__ f0,
              const float* __restrict__ f1,
              const float* __restrict__ f2,
              const float* __restrict__ Uin,
              const float* __restrict__ gamma,
              const float* __restrict__ W_in,
              const float* __restrict__ W_out,
              float* __restrict__ out)
{
    // symmetrized U, upper triangle a<=b packed: sUp[ab][c], c padded to 12
    __shared__ float sUp[45][12];                 // 2.1 KB
    __shared__ float s_h[NB][9][KCH];             // 9.2 KB
    __shared__ float s_tp[NB][9][PCH];            // 18.4 KB; dead after lin_out
                                                  // reads -> reused for exchange
    // exchange view over s_tp: s_part[wave][j=n*9+m][kk], 2*18*128*4B = 18.4KB
    float (*s_part)[18][KCH] = reinterpret_cast<float (*)[18][KCH]>(&s_tp[0][0][0]);

    const int tid = threadIdx.x;      // 0..127
    const int w   = tid >> 6;         // wave: 0 or 1 (uniform per wave)
    const int ln  = tid & 63;
    const int kk  = tid;              // owned channel for RMS/skip/output
    const int node0 = blockIdx.x * NB;

    // ---- build symmetrized padded U in LDS (once per block)
    for (int idx = tid; idx < 45 * 12; idx += NTHR) {
        const int ab = idx / 12;
        const int c  = idx % 12;
        int a = 0, r = ab;
        while (r >= 9 - a) { r -= 9 - a; ++a; }
        const int b = a + r;
        float v = 0.0f;
        if (c < 9) {
            v = Uin[(a * 9 + b) * 9 + c];
            if (a != b) v += Uin[(b * 9 + a) * 9 + c];
        }
        sUp[ab][c] = v;
    }

    // ---- initial feats: thread owns channel kk for BOTH nodes, all 9 m
    float f[NB][9];
    #pragma unroll
    for (int n = 0; n < NB; ++n) {
        const int ng = node0 + n;
        f[n][0] = f0[ng * KCH + kk];
        #pragma unroll
        for (int m = 0; m < 3; ++m) f[n][1 + m] = f1[(ng * 3 + m) * KCH + kk];
        #pragma unroll
        for (int m = 0; m < 5; ++m) f[n][4 + m] = f2[(ng * 5 + m) * KCH + kk];
    }

    for (int it = 0; it < NITER; ++it) {
        // ---------- step 1: equivariant RMS norm -> s_h ----------
        {
            const float g0 = gamma[(it * 3 + 0) * KCH + kk];
            const float g1 = gamma[(it * 3 + 1) * KCH + kk];
            const float g2 = gamma[(it * 3 + 2) * KCH + kk];
            #pragma unroll
            for (int n = 0; n < NB; ++n) {
                const float s0 = f[n][0] * f[n][0];
                const float s1 = f[n][1] * f[n][1] + f[n][2] * f[n][2] + f[n][3] * f[n][3];
                const float s2 = f[n][4] * f[n][4] + f[n][5] * f[n][5] + f[n][6] * f[n][6]
                               + f[n][7] * f[n][7] + f[n][8] * f[n][8];
                const float r0 = rsqrtf(s0 + 1e-6f) * g0;
                const float r1 = rsqrtf(s1 * (1.0f / 3.0f) + 1e-6f) * g1;
                const float r2 = rsqrtf(s2 * (1.0f / 5.0f) + 1e-6f) * g2;
                s_h[n][0][kk] = f[n][0] * r0;
                s_h[n][1][kk] = f[n][1] * r1;
                s_h[n][2][kk] = f[n][2] * r1;
                s_h[n][3][kk] = f[n][3] * r1;
                s_h[n][4][kk] = f[n][4] * r2;
                s_h[n][5][kk] = f[n][5] * r2;
                s_h[n][6][kk] = f[n][6] * r2;
                s_h[n][7][kk] = f[n][7] * r2;
                s_h[n][8][kk] = f[n][8] * r2;
            }
        }
        __syncthreads();   // s_h visible (also orders sUp build on it==0)

        // ---------- step 2: linear_in, TN=2 packed: hc2[n][m] = (colA, colB)
        v2f hc2[NB][9];
        {
            const float* W0 = W_in + (size_t)(it * 3 + 0) * KCH * PCH + 2 * tid;
            const float* W1 = W_in + (size_t)(it * 3 + 1) * KCH * PCH + 2 * tid;
            const float* W2 = W_in + (size_t)(it * 3 + 2) * KCH * PCH + 2 * tid;
            #pragma unroll
            for (int n = 0; n < NB; ++n)
                #pragma unroll
                for (int m = 0; m < 9; ++m) hc2[n][m] = 0.0f;

            #pragma unroll 1
            for (int kb = 0; kb < KCH; kb += 4) {
                v2f wv[3][4];
                #pragma unroll
                for (int r = 0; r < 4; ++r) {
                    wv[0][r] = *(const v2f*)&W0[(kb + r) * PCH];
                    wv[1][r] = *(const v2f*)&W1[(kb + r) * PCH];
                    wv[2][r] = *(const v2f*)&W2[(kb + r) * PCH];
                }
                #pragma unroll
                for (int n = 0; n < NB; ++n) {
                    #pragma unroll
                    for (int m = 0; m < 9; ++m) {
                        const int lm = (m == 0) ? 0 : ((m < 4) ? 1 : 2);
                        const float4 h4 = *(const float4*)&s_h[n][m][kb];
                        v2f acc = hc2[n][m];
                        acc = PKFMA((v2f)(h4.x), wv[lm][0], acc);
                        acc = PKFMA((v2f)(h4.y), wv[lm][1], acc);
                        acc = PKFMA((v2f)(h4.z), wv[lm][2], acc);
                        acc = PKFMA((v2f)(h4.w), wv[lm][3], acc);
                        hc2[n][m] = acc;
                    }
                }
            }
        }

        // ---------- step 3: CG tensor product, packed over (colA, colB) ----------
        {
            v2f tp2[NB][9];
            #pragma unroll
            for (int n = 0; n < NB; ++n)
                #pragma unroll
                for (int c = 0; c < 9; ++c) tp2[n][c] = 0.0f;

            int ab = 0;
            #pragma unroll
            for (int a = 0; a < 9; ++a) {
                #pragma unroll
                for (int b = a; b < 9; ++b) {
                    const v2f q0 = hc2[0][a] * hc2[0][b];   // (qA0, qB0)
                    const v2f q1 = hc2[1][a] * hc2[1][b];   // (qA1, qB1)
                    const float4 u0 = *(const float4*)&sUp[ab][0];
                    const float4 u1 = *(const float4*)&sUp[ab][4];
                    const float  u8 = sUp[ab][8];
                    const float uu[9] = {u0.x, u0.y, u0.z, u0.w, u1.x, u1.y, u1.z, u1.w, u8};
                    #pragma unroll
                    for (int c = 0; c < 9; ++c) {
                        const v2f uc = (v2f)(uu[c]);
                        tp2[0][c] = PKFMA(uc, q0, tp2[0][c]);
                        tp2[1][c] = PKFMA(uc, q1, tp2[1][c]);
                    }
                    ++ab;
                }
            }
            // paired columns -> single ds_write_b64 each
            #pragma unroll
            for (int n = 0; n < NB; ++n)
                #pragma unroll
                for (int c = 0; c < 9; ++c)
                    *(v2f*)&s_tp[n][c][2 * tid] = tp2[n][c];
        }
        __syncthreads();   // s_tp visible to all columns

        // ---------- step 4: linear_out, p-half per wave, packed over kk-pair
        v2f oa2[NB][9];   // (kkA = 2*ln, kkB = 2*ln+1)
        {
            const float* V0 = W_out + (size_t)(it * 3 + 0) * PCH * KCH + 2 * ln;
            const float* V1 = W_out + (size_t)(it * 3 + 1) * PCH * KCH + 2 * ln;
            const float* V2 = W_out + (size_t)(it * 3 + 2) * PCH * KCH + 2 * ln;
            const int pb0 = w * 128;   // this wave's p-half (uniform)

            #pragma unroll
            for (int n = 0; n < NB; ++n)
                #pragma unroll
                for (int m = 0; m < 9; ++m) oa2[n][m] = 0.0f;

            #pragma unroll 1
            for (int pb = 0; pb < 128; pb += 4) {
                v2f vv[3][4];
                #pragma unroll
                for (int r = 0; r < 4; ++r) {
                    const size_t row = (size_t)(pb0 + pb + r) * KCH;
                    vv[0][r] = *(const v2f*)&V0[row];
                    vv[1][r] = *(const v2f*)&V1[row];
                    vv[2][r] = *(const v2f*)&V2[row];
                }
                #pragma unroll
                for (int n = 0; n < NB; ++n) {
                    #pragma unroll
                    for (int m = 0; m < 9; ++m) {
                        const int lm = (m == 0) ? 0 : ((m < 4) ? 1 : 2);
                        const float4 t4 = *(const float4*)&s_tp[n][m][pb0 + pb];
                        v2f acc = oa2[n][m];
                        acc = PKFMA((v2f)(t4.x), vv[lm][0], acc);
                        acc = PKFMA((v2f)(t4.y), vv[lm][1], acc);
                        acc = PKFMA((v2f)(t4.z), vv[lm][2], acc);
                        acc = PKFMA((v2f)(t4.w), vv[lm][3], acc);
                        oa2[n][m] = acc;
                    }
                }
            }
        }
        __syncthreads();   // ALL s_tp reads done -> safe to overwrite as s_part

        // exchange: both waves write their partials for their kk-pair; each
        // thread then sums the two wave-partials at its own kk column.
        #pragma unroll
        for (int n = 0; n < NB; ++n)
            #pragma unroll
            for (int m = 0; m < 9; ++m)
                *(v2f*)&s_part[w][n * 9 + m][2 * ln] = oa2[n][m];
        __syncthreads();

        #pragma unroll
        for (int n = 0; n < NB; ++n)
            #pragma unroll
            for (int m = 0; m < 9; ++m)
                f[n][m] += s_part[0][n * 9 + m][kk] + s_part[1][n * 9 + m][kk];
        __syncthreads();   // s_part reads done before next iter's TP rewrites s_tp
    }

    // ---------- store packed output (N, 9, K)
    #pragma unroll
    for (int n = 0; n < NB; ++n) {
        const int ng = node0 + n;
        #pragma unroll
        for (int m = 0; m < 9; ++m)
            out[(size_t)(ng * 9 + m) * KCH + kk] = f[n][m];
    }
}

extern "C" void kernel_launch(void* const* d_in, const int* in_sizes, int n_in,
                              void* d_out, int out_size, void* d_ws, size_t ws_size,
                              hipStream_t stream) {
    const float* f0    = (const float*)d_in[0];
    const float* f1    = (const float*)d_in[1];
    const float* f2    = (const float*)d_in[2];
    const float* U     = (const float*)d_in[3];
    const float* gamma = (const float*)d_in[4];
    const float* W_in  = (const float*)d_in[5];
    const float* W_out = (const float*)d_in[6];
    float* out = (float*)d_out;

    dim3 grid(NNODES / NB);   // 50000 / 2 = 25000, exact
    dim3 block(NTHR);
    hipLaunchKernelGGL(cg_fused, grid, block, 0, stream,
                       f0, f1, f2, U, gamma, W_in, W_out, out);
}